// Round 9
// baseline (194.556 us; speedup 1.0000x reference)
//
#include <hip/hip_runtime.h>

#define NNODES 50000
#define FEAT 256
#define NH 8
#define DHEAD 32
#define DEG 16
#define CDIM 256  // NH*DHEAD

typedef __attribute__((ext_vector_type(4))) float floatx4;
typedef __attribute__((ext_vector_type(8))) short shortx8;
typedef __attribute__((ext_vector_type(8))) unsigned short ushortx8;
typedef __attribute__((ext_vector_type(4))) int intx4;

__device__ __forceinline__ unsigned short f2bf(float f) {
  union { float f; unsigned u; } v; v.f = f;
  unsigned r = v.u + 0x7fffu + ((v.u >> 16) & 1u);  // RN-even
  return (unsigned short)(r >> 16);
}
__device__ __forceinline__ float bf2f(unsigned short b) {
  union { unsigned u; float f; } v; v.u = ((unsigned)b) << 16;
  return v.f;
}

// Kernel 0: W [H][F][DH] fp32 -> Wt2 bf16 in MFMA-fragment-major order.
__global__ __launch_bounds__(256) void convert_wt(
    const float* __restrict__ W, unsigned short* __restrict__ Wt2) {
  int t = blockIdx.x * 256 + threadIdx.x;
#pragma unroll
  for (int p = 0; p < 4; ++p) {
    int idx = t * 4 + p;  // [0, 65536)
    int jj = idx & 7;
    int l = (idx >> 3) & 63;
    int kt = (idx >> 9) & 7;
    int cgrp = idx >> 12;
    int c = cgrp * 16 + (l & 15);
    int f = kt * 32 + ((l >> 4) << 3) + jj;
    Wt2[idx] = f2bf(W[(size_t)(c >> 5) * (FEAT * DHEAD) + (size_t)f * DHEAD + (c & 31)]);
  }
}

// Kernel 1 (fused): Whb (HEAD-MAJOR [H][N][32]) = bf16(h @ W + bW), plus
// HEAD-MAJOR s1h[h][n] / s2h[h][n] (s2 includes a_bias).
// Swapped-operand MFMA epilogue (R7): lane holds 4 consecutive cols per node
// -> 8B ushort4 Whb stores, quad-only s1/s2 reduction (32 shfls total).
__global__ __launch_bounds__(256) void gemm_fused(
    const float* __restrict__ h, const unsigned short* __restrict__ Wt2,
    const float* __restrict__ bW, const float* __restrict__ a_src,
    const float* __restrict__ a_dst, const float* __restrict__ a_bias,
    unsigned short* __restrict__ Whb, float* __restrict__ s1h,
    float* __restrict__ s2h) {
  __shared__ unsigned short As2[8 * 4 * 64 * 8];  // 32 KB, fragment-major
  const int tid = threadIdx.x;
  const int w = tid >> 6, lane = tid & 63;
  const int mrow = lane & 15, quad = lane >> 4;
  const int row0 = blockIdx.x * 64;

  {  // Stage A once: thread covers (row = w*16 + mrow, cols quad*8..+8) x 8 kt
    int grow = row0 + w * 16 + mrow;
    if (grow > NNODES - 1) grow = NNODES - 1;
    const float* hp = h + (size_t)grow * FEAT + quad * 8;
#pragma unroll
    for (int kt = 0; kt < 8; ++kt) {
      float4 v0 = *(const float4*)(hp + kt * 32);
      float4 v1 = *(const float4*)(hp + kt * 32 + 4);
      shortx8 a8;
      a8[0] = (short)f2bf(v0.x); a8[1] = (short)f2bf(v0.y);
      a8[2] = (short)f2bf(v0.z); a8[3] = (short)f2bf(v0.w);
      a8[4] = (short)f2bf(v1.x); a8[5] = (short)f2bf(v1.y);
      a8[6] = (short)f2bf(v1.z); a8[7] = (short)f2bf(v1.w);
      *(shortx8*)&As2[((kt * 4 + w) * 64 + lane) * 8] = a8;
    }
  }
  __syncthreads();

  floatx4 acc[4][4] = {};  // acc[mi = c-subtile][ni = n-subtile]
#pragma unroll
  for (int kt = 0; kt < 8; ++kt) {
    shortx8 af[4], bfr[4];
#pragma unroll
    for (int mi = 0; mi < 4; ++mi) {
      int cgrp = w * 4 + mi;
      bfr[mi] = *(const shortx8*)&Wt2[((size_t)(cgrp * 8 + kt) * 64 + lane) * 8];
    }
#pragma unroll
    for (int ni = 0; ni < 4; ++ni)
      af[ni] = *(const shortx8*)&As2[((kt * 4 + ni) * 64 + lane) * 8];
#pragma unroll
    for (int mi = 0; mi < 4; ++mi)
#pragma unroll
      for (int ni = 0; ni < 4; ++ni)
        acc[mi][ni] = __builtin_amdgcn_mfma_f32_16x16x32_bf16(
            bfr[mi], af[ni], acc[mi][ni], 0, 0, 0);  // A=Wt, B=h (swapped)
  }

  // Epilogue: lane (mrow, quad) holds, per (mi, ni), node n = row0+ni*16+mrow,
  // cols c0..c0+4 with c0 = w*64 + mi*16 + quad*4.
  float4 bw4[4], as4[4], ad4[4];
#pragma unroll
  for (int mi = 0; mi < 4; ++mi) {
    int c0 = w * 64 + mi * 16 + quad * 4;
    bw4[mi] = *(const float4*)&bW[c0];
    as4[mi] = *(const float4*)&a_src[c0];
    ad4[mi] = *(const float4*)&a_dst[c0];
  }
  float ab0 = a_bias[w * 2], ab1 = a_bias[w * 2 + 1];

#pragma unroll
  for (int ni = 0; ni < 4; ++ni) {
    int n = row0 + ni * 16 + mrow;
    bool ok = n < NNODES;
    float p1h0 = 0.f, p1h1 = 0.f, p2h0 = 0.f, p2h1 = 0.f;
#pragma unroll
    for (int mi = 0; mi < 4; ++mi) {
      int c0 = w * 64 + mi * 16 + quad * 4;
      float v0 = acc[mi][ni][0] + bw4[mi].x;
      float v1 = acc[mi][ni][1] + bw4[mi].y;
      float v2 = acc[mi][ni][2] + bw4[mi].z;
      float v3 = acc[mi][ni][3] + bw4[mi].w;
      ushort4 u;
      u.x = f2bf(v0); u.y = f2bf(v1); u.z = f2bf(v2); u.w = f2bf(v3);
      if (ok)
        *(ushort4*)&Whb[(size_t)(c0 >> 5) * ((size_t)NNODES * 32) +
                        (size_t)n * 32 + (c0 & 31)] = u;
      float d1 = v0 * as4[mi].x + v1 * as4[mi].y + v2 * as4[mi].z + v3 * as4[mi].w;
      float d2 = v0 * ad4[mi].x + v1 * ad4[mi].y + v2 * ad4[mi].z + v3 * ad4[mi].w;
      if (mi < 2) { p1h0 += d1; p2h0 += d2; }
      else        { p1h1 += d1; p2h1 += d2; }
    }
    // reduce over quad (lane bits 4,5); mrow lanes are independent nodes
    p1h0 += __shfl_xor(p1h0, 16); p1h0 += __shfl_xor(p1h0, 32);
    p1h1 += __shfl_xor(p1h1, 16); p1h1 += __shfl_xor(p1h1, 32);
    p2h0 += __shfl_xor(p2h0, 16); p2h0 += __shfl_xor(p2h0, 32);
    p2h1 += __shfl_xor(p2h1, 16); p2h1 += __shfl_xor(p2h1, 32);
    if (quad == 0 && ok) {
      s1h[(size_t)(w * 2) * NNODES + n] = p1h0;
      s1h[(size_t)(w * 2 + 1) * NNODES + n] = p1h1;
      s2h[(size_t)(w * 2) * NNODES + n] = p2h0 + ab0;
      s2h[(size_t)(w * 2 + 1) * NNODES + n] = p2h1 + ab1;
    }
  }
}

// Kernel 2: PERSISTENT software-pipelined head-partitioned gather.
// Head hh = blockIdx&7 pinned to one XCD (keeps the verified L2 residency:
// slab 3.2 MB + s1h 0.2 + s2h 0.2). 96 blocks/head; each wave loops over
// node-groups with stride 96, 2-stage pipeline: iteration i's src row (the
// HBM-latency link that heads every dependency chain) is prefetched during
// iteration i-1's gathers/accumulate. Zero launch churn (768 blocks total,
// all resident), ~25 loads in flight per wave for the whole kernel.
// Per-iter wave = 16 nodes: lane = (node = lane>>2, colchunk c = lane&3);
// quad covers a 64B row slice; softmax w/o max-subtraction (scores
// ~N(0,3.8^2), fp32-exp-safe), quad sum via 2 shfl_xor.
__global__ __launch_bounds__(256, 3) void aggregate(
    const unsigned short* __restrict__ Whb, const float* __restrict__ s1h,
    const float* __restrict__ s2h, const int* __restrict__ src,
    float* __restrict__ out) {
  const int lane = threadIdx.x & 63;
  const int wv = threadIdx.x >> 6;
  const int b = blockIdx.x;
  const int hh = b & 7;            // head == XCD (perf heuristic only)
  const int c = lane & 3;          // col chunk: cols hh*32 + c*8 .. +8
  const int nl = lane >> 2;        // node-in-wave [0,16)
  const unsigned short* Wh = Whb + (size_t)hh * ((size_t)NNODES * 32) + c * 8;
  const float* s1p = s1h + (size_t)hh * NNODES;
  const float* s2p = s2h + (size_t)hh * NNODES;
  const int NG = (NNODES + 63) / 64;  // 782 node-groups per head
  const int BPH = 96;                 // blocks per head

  // ---- prologue: prefetch iteration 0's src row ----
  int g = b >> 3;  // [0, 96)
  int n = g * 64 + wv * 16 + nl;
  bool vcur = n < NNODES;
  int ncl = vcur ? n : NNODES - 1;
  const intx4* sp0 = (const intx4*)&src[(size_t)ncl * DEG];
  intx4 p0 = __builtin_nontemporal_load(sp0);
  intx4 p1 = __builtin_nontemporal_load(sp0 + 1);
  intx4 p2 = __builtin_nontemporal_load(sp0 + 2);
  intx4 p3 = __builtin_nontemporal_load(sp0 + 3);

  while (true) {
    // ---- score-operand loads first (earliest dependent use) ----
    intx4 se = c == 0 ? p0 : (c == 1 ? p1 : (c == 2 ? p2 : p3));
    float a0 = s1p[se.x], a1 = s1p[se.y], a2 = s1p[se.z], a3 = s1p[se.w];
    float s2n = s2p[ncl];  // a_bias folded in

    // ---- 16 independent row gathers (consumed last, deep in flight) ----
    ushortx8 v0  = *(const ushortx8*)&Wh[(size_t)p0.x * 32];
    ushortx8 v1  = *(const ushortx8*)&Wh[(size_t)p0.y * 32];
    ushortx8 v2  = *(const ushortx8*)&Wh[(size_t)p0.z * 32];
    ushortx8 v3  = *(const ushortx8*)&Wh[(size_t)p0.w * 32];
    ushortx8 v4  = *(const ushortx8*)&Wh[(size_t)p1.x * 32];
    ushortx8 v5  = *(const ushortx8*)&Wh[(size_t)p1.y * 32];
    ushortx8 v6  = *(const ushortx8*)&Wh[(size_t)p1.z * 32];
    ushortx8 v7  = *(const ushortx8*)&Wh[(size_t)p1.w * 32];
    ushortx8 v8  = *(const ushortx8*)&Wh[(size_t)p2.x * 32];
    ushortx8 v9  = *(const ushortx8*)&Wh[(size_t)p2.y * 32];
    ushortx8 v10 = *(const ushortx8*)&Wh[(size_t)p2.z * 32];
    ushortx8 v11 = *(const ushortx8*)&Wh[(size_t)p2.w * 32];
    ushortx8 v12 = *(const ushortx8*)&Wh[(size_t)p3.x * 32];
    ushortx8 v13 = *(const ushortx8*)&Wh[(size_t)p3.y * 32];
    ushortx8 v14 = *(const ushortx8*)&Wh[(size_t)p3.z * 32];
    ushortx8 v15 = *(const ushortx8*)&Wh[(size_t)p3.w * 32];

    // ---- prefetch next iteration's src row (hides HBM latency) ----
    int gn = g + BPH;
    int nn = gn * 64 + wv * 16 + nl;
    bool vnx = nn < NNODES;
    int nncl = vnx ? nn : NNODES - 1;
    intx4 q0 = {0, 0, 0, 0}, q1 = {0, 0, 0, 0};
    intx4 q2 = {0, 0, 0, 0}, q3 = {0, 0, 0, 0};
    if (gn < NG) {  // block-uniform branch
      const intx4* sq = (const intx4*)&src[(size_t)nncl * DEG];
      q0 = __builtin_nontemporal_load(sq);
      q1 = __builtin_nontemporal_load(sq + 1);
      q2 = __builtin_nontemporal_load(sq + 2);
      q3 = __builtin_nontemporal_load(sq + 3);
    }

    // ---- softmax (operands already in flight; no max-subtraction) ----
    float t0 = a0 + s2n, t1 = a1 + s2n, t2 = a2 + s2n, t3 = a3 + s2n;
    t0 = t0 > 0.f ? t0 : 0.2f * t0;
    t1 = t1 > 0.f ? t1 : 0.2f * t1;
    t2 = t2 > 0.f ? t2 : 0.2f * t2;
    t3 = t3 > 0.f ? t3 : 0.2f * t3;
    float e0 = __expf(t0), e1 = __expf(t1), e2 = __expf(t2), e3 = __expf(t3);
    float sum = (e0 + e1) + (e2 + e3);
    sum += __shfl_xor(sum, 1);
    sum += __shfl_xor(sum, 2);
    float inv = 1.f / sum;

    // ---- weighted accumulate: 16 edges x 8 cols per lane ----
    float acc0 = 0.f, acc1 = 0.f, acc2 = 0.f, acc3 = 0.f;
    float acc4 = 0.f, acc5 = 0.f, acc6 = 0.f, acc7 = 0.f;
#define STEP(K, EV, VV)                                            \
    {                                                              \
      float wk = __shfl(EV, (lane & 60) | (K >> 2)) * inv;         \
      acc0 += wk * bf2f(VV[0]); acc1 += wk * bf2f(VV[1]);          \
      acc2 += wk * bf2f(VV[2]); acc3 += wk * bf2f(VV[3]);          \
      acc4 += wk * bf2f(VV[4]); acc5 += wk * bf2f(VV[5]);          \
      acc6 += wk * bf2f(VV[6]); acc7 += wk * bf2f(VV[7]);          \
    }
    STEP(0, e0, v0)   STEP(1, e1, v1)   STEP(2, e2, v2)   STEP(3, e3, v3)
    STEP(4, e0, v4)   STEP(5, e1, v5)   STEP(6, e2, v6)   STEP(7, e3, v7)
    STEP(8, e0, v8)   STEP(9, e1, v9)   STEP(10, e2, v10) STEP(11, e3, v11)
    STEP(12, e0, v12) STEP(13, e1, v13) STEP(14, e2, v14) STEP(15, e3, v15)
#undef STEP

    if (vcur) {
      float* op = &out[(size_t)n * CDIM + hh * 32 + c * 8];
      floatx4 o0, o1;
      o0.x = acc0; o0.y = acc1; o0.z = acc2; o0.w = acc3;
      o1.x = acc4; o1.y = acc5; o1.z = acc6; o1.w = acc7;
      __builtin_nontemporal_store(o0, (floatx4*)op);
      __builtin_nontemporal_store(o1, (floatx4*)(op + 4));
    }

    g = gn;
    if (g >= NG) break;
    n = nn; ncl = nncl; vcur = vnx;
    p0 = q0; p1 = q1; p2 = q2; p3 = q3;
  }
}

extern "C" void kernel_launch(void* const* d_in, const int* in_sizes, int n_in,
                              void* d_out, int out_size, void* d_ws, size_t ws_size,
                              hipStream_t stream) {
  const float* h = (const float*)d_in[0];
  const float* W = (const float*)d_in[1];
  const float* bW = (const float*)d_in[2];
  const float* a_src = (const float*)d_in[3];
  const float* a_dst = (const float*)d_in[4];
  const float* a_bias = (const float*)d_in[5];
  const int* src = (const int*)d_in[6];
  // d_in[7] (dst) unused: dst = repeat(arange(N), DEG) structurally.
  float* out = (float*)d_out;

  unsigned short* Whb = (unsigned short*)d_ws;          // [8][N][32] bf16, 25.6 MB
  unsigned short* Wt2 = Whb + (size_t)NNODES * CDIM;    // [256][256] bf16, 131 KB
  float* s1h = (float*)(Wt2 + CDIM * FEAT);             // [8][N] fp32, 1.6 MB
  float* s2h = s1h + (size_t)NH * NNODES;               // [8][N] fp32, 1.6 MB

  convert_wt<<<64, 256, 0, stream>>>(W, Wt2);
  gemm_fused<<<(NNODES + 63) / 64, 256, 0, stream>>>(h, Wt2, bW, a_src, a_dst,
                                                     a_bias, Whb, s1h, s2h);
  // Persistent: 8 heads x 96 blocks, each block loops over its node-groups
  // with a 2-stage src prefetch pipeline. hh = blockIdx & 7 pins each head's
  // resident set to one XCD's L2.
  aggregate<<<8 * 96, 256, 0, stream>>>(Whb, s1h, s2h, src, out);
}

// Round 10
// 171.774 us; speedup vs baseline: 1.1326x; 1.1326x over previous
//
#include <hip/hip_runtime.h>

#define NNODES 50000
#define FEAT 256
#define NH 8
#define DHEAD 32
#define DEG 16
#define CDIM 256  // NH*DHEAD

typedef __attribute__((ext_vector_type(4))) float floatx4;
typedef __attribute__((ext_vector_type(8))) short shortx8;
typedef __attribute__((ext_vector_type(8))) unsigned short ushortx8;
typedef __attribute__((ext_vector_type(4))) int intx4;
typedef __attribute__((ext_vector_type(4))) _Float16 halfx4;

__device__ __forceinline__ unsigned short f2bf(float f) {
  union { float f; unsigned u; } v; v.f = f;
  unsigned r = v.u + 0x7fffu + ((v.u >> 16) & 1u);  // RN-even
  return (unsigned short)(r >> 16);
}
__device__ __forceinline__ float bf2f(unsigned short b) {
  union { unsigned u; float f; } v; v.u = ((unsigned)b) << 16;
  return v.f;
}

// Kernel 0: W [H][F][DH] fp32 -> Wt2 bf16 in MFMA-fragment-major order.
__global__ __launch_bounds__(256) void convert_wt(
    const float* __restrict__ W, unsigned short* __restrict__ Wt2) {
  int t = blockIdx.x * 256 + threadIdx.x;
#pragma unroll
  for (int p = 0; p < 4; ++p) {
    int idx = t * 4 + p;  // [0, 65536)
    int jj = idx & 7;
    int l = (idx >> 3) & 63;
    int kt = (idx >> 9) & 7;
    int cgrp = idx >> 12;
    int c = cgrp * 16 + (l & 15);
    int f = kt * 32 + ((l >> 4) << 3) + jj;
    Wt2[idx] = f2bf(W[(size_t)(c >> 5) * (FEAT * DHEAD) + (size_t)f * DHEAD + (c & 31)]);
  }
}

// Kernel 1 (fused): Whb (HEAD-MAJOR [H][N][32]) = bf16(h @ W + bW), plus
// NODE-MAJOR s1g[n][8] / s2g[n][8] (s2 includes a_bias) so the scores
// kernel reads all 8 heads of a source node with ONE 32B line lookup.
// Swapped-operand MFMA epilogue (R7): lane holds 4 consecutive cols per node
// -> 8B ushort4 Whb stores, quad-only s1/s2 reduction.
__global__ __launch_bounds__(256) void gemm_fused(
    const float* __restrict__ h, const unsigned short* __restrict__ Wt2,
    const float* __restrict__ bW, const float* __restrict__ a_src,
    const float* __restrict__ a_dst, const float* __restrict__ a_bias,
    unsigned short* __restrict__ Whb, float* __restrict__ s1g,
    float* __restrict__ s2g) {
  __shared__ unsigned short As2[8 * 4 * 64 * 8];  // 32 KB, fragment-major
  const int tid = threadIdx.x;
  const int w = tid >> 6, lane = tid & 63;
  const int mrow = lane & 15, quad = lane >> 4;
  const int row0 = blockIdx.x * 64;

  {  // Stage A once: thread covers (row = w*16 + mrow, cols quad*8..+8) x 8 kt
    int grow = row0 + w * 16 + mrow;
    if (grow > NNODES - 1) grow = NNODES - 1;
    const float* hp = h + (size_t)grow * FEAT + quad * 8;
#pragma unroll
    for (int kt = 0; kt < 8; ++kt) {
      float4 v0 = *(const float4*)(hp + kt * 32);
      float4 v1 = *(const float4*)(hp + kt * 32 + 4);
      shortx8 a8;
      a8[0] = (short)f2bf(v0.x); a8[1] = (short)f2bf(v0.y);
      a8[2] = (short)f2bf(v0.z); a8[3] = (short)f2bf(v0.w);
      a8[4] = (short)f2bf(v1.x); a8[5] = (short)f2bf(v1.y);
      a8[6] = (short)f2bf(v1.z); a8[7] = (short)f2bf(v1.w);
      *(shortx8*)&As2[((kt * 4 + w) * 64 + lane) * 8] = a8;
    }
  }
  __syncthreads();

  floatx4 acc[4][4] = {};  // acc[mi = c-subtile][ni = n-subtile]
#pragma unroll
  for (int kt = 0; kt < 8; ++kt) {
    shortx8 af[4], bfr[4];
#pragma unroll
    for (int mi = 0; mi < 4; ++mi) {
      int cgrp = w * 4 + mi;
      bfr[mi] = *(const shortx8*)&Wt2[((size_t)(cgrp * 8 + kt) * 64 + lane) * 8];
    }
#pragma unroll
    for (int ni = 0; ni < 4; ++ni)
      af[ni] = *(const shortx8*)&As2[((kt * 4 + ni) * 64 + lane) * 8];
#pragma unroll
    for (int mi = 0; mi < 4; ++mi)
#pragma unroll
      for (int ni = 0; ni < 4; ++ni)
        acc[mi][ni] = __builtin_amdgcn_mfma_f32_16x16x32_bf16(
            bfr[mi], af[ni], acc[mi][ni], 0, 0, 0);  // A=Wt, B=h (swapped)
  }

  // Epilogue: lane (mrow, quad) holds, per (mi, ni), node n = row0+ni*16+mrow,
  // cols c0..c0+4 with c0 = w*64 + mi*16 + quad*4.
  float4 bw4[4], as4[4], ad4[4];
#pragma unroll
  for (int mi = 0; mi < 4; ++mi) {
    int c0 = w * 64 + mi * 16 + quad * 4;
    bw4[mi] = *(const float4*)&bW[c0];
    as4[mi] = *(const float4*)&a_src[c0];
    ad4[mi] = *(const float4*)&a_dst[c0];
  }
  float ab0 = a_bias[w * 2], ab1 = a_bias[w * 2 + 1];

#pragma unroll
  for (int ni = 0; ni < 4; ++ni) {
    int n = row0 + ni * 16 + mrow;
    bool ok = n < NNODES;
    float p1h0 = 0.f, p1h1 = 0.f, p2h0 = 0.f, p2h1 = 0.f;
#pragma unroll
    for (int mi = 0; mi < 4; ++mi) {
      int c0 = w * 64 + mi * 16 + quad * 4;
      float v0 = acc[mi][ni][0] + bw4[mi].x;
      float v1 = acc[mi][ni][1] + bw4[mi].y;
      float v2 = acc[mi][ni][2] + bw4[mi].z;
      float v3 = acc[mi][ni][3] + bw4[mi].w;
      ushort4 u;
      u.x = f2bf(v0); u.y = f2bf(v1); u.z = f2bf(v2); u.w = f2bf(v3);
      if (ok)
        *(ushort4*)&Whb[(size_t)(c0 >> 5) * ((size_t)NNODES * 32) +
                        (size_t)n * 32 + (c0 & 31)] = u;
      float d1 = v0 * as4[mi].x + v1 * as4[mi].y + v2 * as4[mi].z + v3 * as4[mi].w;
      float d2 = v0 * ad4[mi].x + v1 * ad4[mi].y + v2 * ad4[mi].z + v3 * ad4[mi].w;
      if (mi < 2) { p1h0 += d1; p2h0 += d2; }
      else        { p1h1 += d1; p2h1 += d2; }
    }
    // reduce over quad (lane bits 4,5); mrow lanes are independent nodes
    p1h0 += __shfl_xor(p1h0, 16); p1h0 += __shfl_xor(p1h0, 32);
    p1h1 += __shfl_xor(p1h1, 16); p1h1 += __shfl_xor(p1h1, 32);
    p2h0 += __shfl_xor(p2h0, 16); p2h0 += __shfl_xor(p2h0, 32);
    p2h1 += __shfl_xor(p2h1, 16); p2h1 += __shfl_xor(p2h1, 32);
    if (quad == 0 && ok) {
      float2 s1v; s1v.x = p1h0; s1v.y = p1h1;
      float2 s2v; s2v.x = p2h0 + ab0; s2v.y = p2h1 + ab1;
      *(float2*)&s1g[(size_t)n * NH + w * 2] = s1v;
      *(float2*)&s2g[(size_t)n * NH + w * 2] = s2v;
    }
  }
}

// Kernel 1.5: per-edge ALL-HEAD softmax weights, written once as f16.
// Removes the 8x-redundant per-head s1 gathers from aggregate: one 32B
// s1g[src] line lookup serves all 8 heads. Wave = 4 nodes x 16 edges
// (lane = nl<<4 | e); per-head sum via shfl_xor 1/2/4/8 within the node's
// 16 lanes; no max-subtraction (scores ~N(0,3.8^2), fp32-exp-safe).
// attw layout [H][N][16] f16: aggregate's per-head slab = 1.6 MB, and the
// wave's stores coalesce (16 consecutive e per node per head).
__global__ __launch_bounds__(256) void scores(
    const float* __restrict__ s1g, const float* __restrict__ s2g,
    const int* __restrict__ src, _Float16* __restrict__ attw) {
  const int lane = threadIdx.x & 63;
  const int wv = threadIdx.x >> 6;
  const int nl = lane >> 4, e = lane & 15;
  const int n = blockIdx.x * 16 + wv * 4 + nl;

  int s = src[(size_t)n * DEG + e];
  float4 f1a = *(const float4*)&s1g[(size_t)s * NH];
  float4 f1b = *(const float4*)&s1g[(size_t)s * NH + 4];
  float4 f2a = *(const float4*)&s2g[(size_t)n * NH];
  float4 f2b = *(const float4*)&s2g[(size_t)n * NH + 4];

  float sc[8];
  sc[0] = f1a.x + f2a.x; sc[1] = f1a.y + f2a.y;
  sc[2] = f1a.z + f2a.z; sc[3] = f1a.w + f2a.w;
  sc[4] = f1b.x + f2b.x; sc[5] = f1b.y + f2b.y;
  sc[6] = f1b.z + f2b.z; sc[7] = f1b.w + f2b.w;
  float ex[8], sm[8];
#pragma unroll
  for (int hh = 0; hh < 8; ++hh) {
    float t = sc[hh];
    t = t > 0.f ? t : 0.2f * t;  // leaky relu (a_bias folded into s2g)
    ex[hh] = __expf(t);
    float su = ex[hh];
    su += __shfl_xor(su, 1);
    su += __shfl_xor(su, 2);
    su += __shfl_xor(su, 4);
    su += __shfl_xor(su, 8);
    sm[hh] = su;
  }
#pragma unroll
  for (int hh = 0; hh < 8; ++hh) {
    float w = ex[hh] * (1.f / sm[hh]);
    attw[(size_t)hh * (NNODES * DEG) + (size_t)n * DEG + e] = (_Float16)w;
  }
}

// Kernel 2: head-partitioned gather (one-shot R7 grid -- persistent variant
// regressed, R9). Head hh = blockIdx&7 pinned to one XCD: resident set =
// Whb slab 3.2 MB + attw slab 1.6 MB < 4 MB L2. No score gathers or softmax
// here anymore: weights arrive as ONE coalesced 8B f16x4 load per lane plus
// 16 quad shfls. Wave = 16 nodes; lane = (node = lane>>2, colchunk c =
// lane&3); full src row per lane (quad-merged loads) -> register-static
// gather addresses, 16 independent 16B gathers in flight.
__global__ __launch_bounds__(256) void aggregate(
    const unsigned short* __restrict__ Whb, const _Float16* __restrict__ attw,
    const int* __restrict__ src, float* __restrict__ out) {
  const int lane = threadIdx.x & 63;
  const int wv = threadIdx.x >> 6;
  const int b = blockIdx.x;
  const int hh = b & 7;            // head == XCD (perf heuristic only)
  const int c = lane & 3;          // col chunk: cols hh*32 + c*8 .. +8
  int n = (b >> 3) * 64 + wv * 16 + (lane >> 2);
  const bool valid = n < NNODES;
  if (!valid) n = NNODES - 1;      // clamp: safe loads, store skipped

  // This lane's 4 weights (edges c*4 .. c*4+3), one coalesced 8B load.
  halfx4 w4 = *(const halfx4*)&attw[(size_t)hh * (NNODES * DEG) +
                                    (size_t)n * DEG + c * 4];
  float wA = (float)w4[0], wB = (float)w4[1];
  float wC = (float)w4[2], wD = (float)w4[3];

  // Full src row in registers (quad-merged loads).
  const intx4* srow = (const intx4*)&src[(size_t)n * DEG];
  intx4 p0 = srow[0], p1 = srow[1], p2 = srow[2], p3 = srow[3];

  // All 16 row gathers issued before any dependent VALU work.
  const unsigned short* Wh = Whb + (size_t)hh * ((size_t)NNODES * 32) + c * 8;
  ushortx8 v0  = *(const ushortx8*)&Wh[(size_t)p0.x * 32];
  ushortx8 v1  = *(const ushortx8*)&Wh[(size_t)p0.y * 32];
  ushortx8 v2  = *(const ushortx8*)&Wh[(size_t)p0.z * 32];
  ushortx8 v3  = *(const ushortx8*)&Wh[(size_t)p0.w * 32];
  ushortx8 v4  = *(const ushortx8*)&Wh[(size_t)p1.x * 32];
  ushortx8 v5  = *(const ushortx8*)&Wh[(size_t)p1.y * 32];
  ushortx8 v6  = *(const ushortx8*)&Wh[(size_t)p1.z * 32];
  ushortx8 v7  = *(const ushortx8*)&Wh[(size_t)p1.w * 32];
  ushortx8 v8  = *(const ushortx8*)&Wh[(size_t)p2.x * 32];
  ushortx8 v9  = *(const ushortx8*)&Wh[(size_t)p2.y * 32];
  ushortx8 v10 = *(const ushortx8*)&Wh[(size_t)p2.z * 32];
  ushortx8 v11 = *(const ushortx8*)&Wh[(size_t)p2.w * 32];
  ushortx8 v12 = *(const ushortx8*)&Wh[(size_t)p3.x * 32];
  ushortx8 v13 = *(const ushortx8*)&Wh[(size_t)p3.y * 32];
  ushortx8 v14 = *(const ushortx8*)&Wh[(size_t)p3.z * 32];
  ushortx8 v15 = *(const ushortx8*)&Wh[(size_t)p3.w * 32];

  float acc0 = 0.f, acc1 = 0.f, acc2 = 0.f, acc3 = 0.f;
  float acc4 = 0.f, acc5 = 0.f, acc6 = 0.f, acc7 = 0.f;
#define ACC8(WK, VV)                                               \
  {                                                                \
    float wk = (WK);                                               \
    acc0 += wk * bf2f(VV[0]); acc1 += wk * bf2f(VV[1]);            \
    acc2 += wk * bf2f(VV[2]); acc3 += wk * bf2f(VV[3]);            \
    acc4 += wk * bf2f(VV[4]); acc5 += wk * bf2f(VV[5]);            \
    acc6 += wk * bf2f(VV[6]); acc7 += wk * bf2f(VV[7]);            \
  }
#define STEP4(CC, VA, VB, VC, VD)                                  \
  {                                                                \
    int sl = (lane & 60) | CC;                                     \
    ACC8(__shfl(wA, sl), VA); ACC8(__shfl(wB, sl), VB);            \
    ACC8(__shfl(wC, sl), VC); ACC8(__shfl(wD, sl), VD);            \
  }
  STEP4(0, v0, v1, v2, v3)
  STEP4(1, v4, v5, v6, v7)
  STEP4(2, v8, v9, v10, v11)
  STEP4(3, v12, v13, v14, v15)
#undef STEP4
#undef ACC8

  if (valid) {
    float* op = &out[(size_t)n * CDIM + hh * 32 + c * 8];
    floatx4 o0, o1;
    o0.x = acc0; o0.y = acc1; o0.z = acc2; o0.w = acc3;
    o1.x = acc4; o1.y = acc5; o1.z = acc6; o1.w = acc7;
    __builtin_nontemporal_store(o0, (floatx4*)op);
    __builtin_nontemporal_store(o1, (floatx4*)(op + 4));
  }
}

extern "C" void kernel_launch(void* const* d_in, const int* in_sizes, int n_in,
                              void* d_out, int out_size, void* d_ws, size_t ws_size,
                              hipStream_t stream) {
  const float* h = (const float*)d_in[0];
  const float* W = (const float*)d_in[1];
  const float* bW = (const float*)d_in[2];
  const float* a_src = (const float*)d_in[3];
  const float* a_dst = (const float*)d_in[4];
  const float* a_bias = (const float*)d_in[5];
  const int* src = (const int*)d_in[6];
  // d_in[7] (dst) unused: dst = repeat(arange(N), DEG) structurally.
  float* out = (float*)d_out;

  unsigned short* Whb = (unsigned short*)d_ws;          // [8][N][32] bf16, 25.6 MB
  unsigned short* Wt2 = Whb + (size_t)NNODES * CDIM;    // [256][256] bf16, 131 KB
  float* s1g = (float*)(Wt2 + CDIM * FEAT);             // [N][8] fp32, 1.6 MB
  float* s2g = s1g + (size_t)NNODES * NH;               // [N][8] fp32, 1.6 MB
  _Float16* attw = (_Float16*)(s2g + (size_t)NNODES * NH);  // [8][N][16] f16, 12.8 MB

  convert_wt<<<64, 256, 0, stream>>>(W, Wt2);
  gemm_fused<<<(NNODES + 63) / 64, 256, 0, stream>>>(h, Wt2, bW, a_src, a_dst,
                                                     a_bias, Whb, s1g, s2g);
  scores<<<NNODES / 16, 256, 0, stream>>>(s1g, s2g, src, attw);
  // 782 node-groups (64 nodes each) x 8 heads; hh = blockIdx & 7 pins each
  // head's resident set (Whb slab + attw slab) to one XCD's L2.
  aggregate<<<782 * 8, 256, 0, stream>>>(Whb, attw, src, out);
}